// Round 17
// baseline (352.047 us; speedup 1.0000x reference)
//
#include <hip/hip_runtime.h>

typedef _Float16 f16;
typedef _Float16 f16x2 __attribute__((ext_vector_type(2)));
typedef _Float16 f16x8 __attribute__((ext_vector_type(8)));
typedef float f32x4 __attribute__((ext_vector_type(4)));
typedef int i32x4 __attribute__((ext_vector_type(4)));

#define MFMA16(a,b,c) __builtin_amdgcn_mfma_f32_16x16x32_f16(a,b,c,0,0,0)

#define NITEMS 100000
#define NBLK4  1563   // ceil(100000/64)

// ---- workspace byte offsets ----
#define OFF_WIH   0u
#define OFF_WHH   393216u
#define OFF_MNU   786432u
#define OFF_MNU2  851968u
#define OFF_MNEA  1048576u
#define OFF_MLP1  1081344u
#define OFF_MLP2  1212416u
#define OFF_WHHD  1409024u          // row-major f16 W_hh 768x256 (dot2 scan)
#define OFF_GI    1802240u          // 12800x768 f16 (biases folded); later ypart; later raw f16 scores
#define OFF_TV    21463040u         // 12800x128 f16
#define OFF_MN    24739840u         // 50x256x10x128 f16
#define OFF_YALL  57507840u         // 12800x256 f16
#define OFF_SY    64061440u         // 100000x256 f16
#define OFF_Y16   115261440u        // 256x256 f16
#define OFF_PMAX  115392512u        // 256x1600 f32
#define OFF_PSUM  117030912u        // 256x1600 f32
#define OFF_LSE   118669312u        // 256 f32

__device__ __forceinline__ float sigm(float x) { return 1.f / (1.f + __expf(-x)); }
__device__ __forceinline__ float tanh_fast(float x) {
  return 1.f - 2.f / (1.f + __expf(2.f * x));
}
__device__ __forceinline__ float fdot2(f16x2 a, f16x2 b, float c) {
#if defined(__has_builtin)
#if __has_builtin(__builtin_amdgcn_fdot2)
  return __builtin_amdgcn_fdot2(a, b, c, false);
#else
  return fmaf((float)a[1], (float)b[1], fmaf((float)a[0], (float)b[0], c));
#endif
#else
  return fmaf((float)a[1], (float)b[1], fmaf((float)a[0], (float)b[0], c));
#endif
}

// ============================================================================
// Pack weight matrices into f16 MFMA B-fragment streams + row-major Whh_d.
// ============================================================================
__global__ __launch_bounds__(256) void k_pack(
    const float* s0, const float* s1, const float* s2, const float* s3,
    const float* s4, const float* s5, const float* s6, f16* base)
{
  int fid = blockIdx.x * 256 + threadIdx.x;  // 112640 total
  if (fid >= 88064) {
    int g = fid - 88064;                     // 0..24575, 8 f16 each
    const float* sp = s1 + (size_t)g * 8;
    f16* dst = (f16*)((char*)base + OFF_WHHD);
    f16x8 v;
    #pragma unroll
    for (int j = 0; j < 8; j++) v[j] = (f16)sp[j];
    *(f16x8*)(dst + (size_t)g * 8) = v;
    return;
  }
  const float* src; f16* dst; int K, f;
  if (fid < 24576)      { src = s0; dst = base;          K = 256; f = fid; }          // W_ih 768x256
  else if (fid < 49152) { src = s1; dst = base + 196608; K = 256; f = fid - 24576; }  // W_hh 768x256
  else if (fid < 53248) { src = s2; dst = base + 393216; K = 256; f = fid - 49152; }  // MNu_W 128x256
  else if (fid < 65536) { src = s3; dst = base + 425984; K = 384; f = fid - 53248; }  // MNu2_W 256x384
  else if (fid < 67584) { src = s4; dst = base + 524288; K = 128; f = fid - 65536; }  // MNea_W 128x128
  else if (fid < 75776) { src = s5; dst = base + 540672; K = 256; f = fid - 67584; }  // mlp1_W 256x256
  else                  { src = s6; dst = base + 606208; K = 384; f = fid - 75776; }  // mlp2_W 256x384
  int lane = f & 63, t2 = f >> 6, KS = K >> 5;
  int ks = t2 % KS, nt = t2 / KS;
  int row = nt * 16 + (lane & 15), col = ks * 32 + ((lane >> 4) << 3);
  const float* sp = src + (size_t)row * K + col;
  f16x8 v;
  #pragma unroll
  for (int j = 0; j < 8; j++) v[j] = (f16)sp[j];
  *(f16x8*)(dst + (size_t)f * 8) = v;
}

// ============================================================================
//  blocks 0..399    gi = f16(E[X]@W_ih.T + bih [+ bhh for r,z]), LDS-staged
//  blocks 400..799  tv = f16(tanh(KBE[X]@MNea_W.T + b)), LDS-staged
// ============================================================================
__global__ __launch_bounds__(512) void k_prep(
    const int* __restrict__ X, const float* __restrict__ E,
    const f16* __restrict__ Wih_p, const float* __restrict__ bih,
    const float* __restrict__ bhh, f16* __restrict__ gi,
    const float* __restrict__ KBE, const f16* __restrict__ Wea_p,
    const float* __restrict__ bea, f16* __restrict__ tv)
{
  __shared__ __align__(16) char smem[66048];   // At 16896 | Lg2 49152
  f16 (*At)[264] = (f16(*)[264])smem;
  f16* Lg2 = (f16*)(smem + 16896);
  int tid = threadIdx.x;
  int w = tid >> 6, lane = tid & 63, lr = lane & 15, lg = lane >> 4;
  if (blockIdx.x < 400) {
    int r0g = blockIdx.x * 32;        // global row (t*256 + b); one t per block
    int t = r0g >> 8;
    {
      int r = tid >> 4, c = (tid & 15) * 16;
      int b = (r0g + r) & 255;
      int item = X[b * 50 + t];
      if (item == 0) {
        #pragma unroll
        for (int j = 0; j < 16; j++) At[r][c + j] = (f16)0.f;
      } else {
        const float4* sp = (const float4*)(E + (size_t)item * 256 + c);
        #pragma unroll
        for (int q = 0; q < 4; q++) {
          float4 v = sp[q];
          At[r][c + q*4 + 0] = (f16)v.x; At[r][c + q*4 + 1] = (f16)v.y;
          At[r][c + q*4 + 2] = (f16)v.z; At[r][c + q*4 + 3] = (f16)v.w;
        }
      }
    }
    __syncthreads();
    f32x4 acc[2][6] = {};
    for (int ks = 0; ks < 8; ks++) {
      f16x8 a0 = *(const f16x8*)(&At[lr][ks * 32 + lg * 8]);
      f16x8 a1 = *(const f16x8*)(&At[16 + lr][ks * 32 + lg * 8]);
      #pragma unroll
      for (int j = 0; j < 6; j++) {
        int nt = w * 6 + j;
        f16x8 bf = *(const f16x8*)(Wih_p + ((size_t)((nt * 8 + ks) * 64 + lane) << 3));
        acc[0][j] = MFMA16(a0, bf, acc[0][j]);
        acc[1][j] = MFMA16(a1, bf, acc[1][j]);
      }
    }
    #pragma unroll
    for (int j = 0; j < 6; j++) {
      int col = (w * 6 + j) * 16 + lr;
      float bias = bih[col] + (col < 512 ? bhh[col] : 0.f);
      #pragma unroll
      for (int mt = 0; mt < 2; mt++)
        #pragma unroll
        for (int rr = 0; rr < 4; rr++)
          Lg2[(mt * 16 + lg * 4 + rr) * 768 + col] = (f16)(acc[mt][j][rr] + bias);
    }
    __syncthreads();
    f16* dst = gi + (size_t)r0g * 768;
    #pragma unroll
    for (int q = 0; q < 6; q++) {
      int u = q * 512 + tid;
      *(f16x8*)(dst + u * 8) = *(const f16x8*)(Lg2 + u * 8);
    }
  } else {
    int r0 = (blockIdx.x - 400) * 32;
    int t = r0 >> 8;
    {
      int r = tid >> 4, c = (tid & 15) * 8;
      int b = (r0 + r) & 255;
      int item = X[b * 50 + t];
      if (item == 0) {
        #pragma unroll
        for (int j = 0; j < 8; j++) At[r][c + j] = (f16)0.f;
      } else {
        const float4* sp = (const float4*)(KBE + (size_t)item * 128 + c);
        #pragma unroll
        for (int q = 0; q < 2; q++) {
          float4 v = sp[q];
          At[r][c + q*4 + 0] = (f16)v.x; At[r][c + q*4 + 1] = (f16)v.y;
          At[r][c + q*4 + 2] = (f16)v.z; At[r][c + q*4 + 3] = (f16)v.w;
        }
      }
    }
    __syncthreads();
    f32x4 acc[2] = {};
    for (int ks = 0; ks < 4; ks++) {
      f16x8 a0 = *(const f16x8*)(&At[lr][ks * 32 + lg * 8]);
      f16x8 a1 = *(const f16x8*)(&At[16 + lr][ks * 32 + lg * 8]);
      f16x8 bf = *(const f16x8*)(Wea_p + ((size_t)((w * 4 + ks) * 64 + lane) << 3));
      acc[0] = MFMA16(a0, bf, acc[0]);
      acc[1] = MFMA16(a1, bf, acc[1]);
    }
    f16* tvs = Lg2;                    // [32][128]
    int col = w * 16 + lr;
    float bias = bea[col];
    #pragma unroll
    for (int mt = 0; mt < 2; mt++)
      #pragma unroll
      for (int rr = 0; rr < 4; rr++)
        tvs[(mt * 16 + lg * 4 + rr) * 128 + col] = (f16)tanh_fast(acc[mt][rr] + bias);
    __syncthreads();
    {
      int row = tid >> 4, c = (tid & 15) * 8;
      *(f16x8*)(tv + (size_t)(r0 + row) * 128 + c) = *(const f16x8*)(tvs + row * 128 + c);
    }
  }
}

// ============================================================================
// Fused, hardware-enforced 1 block/CU (90KB LDS, 256 blocks, 1024 thr):
//  blocks 0..127    dot2 GRU scan, 2 batch rows each (L2-port bound; VALU well
//                   under the floor, so 2 rows cost the same as 1)
//  blocks 128..151  MN trajectory, grid-strided pairs
//  blocks 152..255  persistent Sy over 3125 tiles (104 dedicated CUs)
// No CU shares its L2 port between scan and Sy.
// ============================================================================
__global__ __launch_bounds__(1024) void k_fused4(
    const f16* __restrict__ Whh_d, const float* __restrict__ bhh,
    const f16* __restrict__ gi, f16* __restrict__ y_all,
    const f16* __restrict__ tv, const float* __restrict__ Rm, f16* __restrict__ MN,
    const float* __restrict__ E, const float* __restrict__ KBE,
    const f16* __restrict__ mlp2_p, const float* __restrict__ mlp2b, f16* __restrict__ Sy)
{
  __shared__ __align__(16) char smem[90112];   // forces 1 block/CU
  int tid = threadIdx.x, w = tid >> 6, l = tid & 63;
  if (blockIdx.x < 128) {
    // ---------------- dot2 GRU scan, 2 rows/block ----------------
    f16* hbuf = (f16*)smem;                  // [2][288] chunk-strided (72/chunk)
    float* ghbuf = (float*)(smem + 2048);    // [2][768]
    int b0 = blockIdx.x * 2;
    int chunk = l >> 4, cl = l & 15;
    i32x4 Wv[3][8];
    #pragma unroll
    for (int j = 0; j < 3; j++) {
      int col = w * 48 + j * 16 + cl;
      const f16* wp = Whh_d + (size_t)col * 256 + chunk * 64;
      #pragma unroll
      for (int m = 0; m < 8; m++)
        Wv[j][m] = *(const i32x4*)(wp + m * 8);
    }
    int q = tid >> 8, c = tid & 255;         // valid for tid<512
    float hprev = 0.f, bN = 0.f;
    f16 gr = (f16)0.f, gz = (f16)0.f, gn = (f16)0.f;
    if (tid < 512) {
      bN = bhh[512 + c];
      const f16* g0 = gi + (size_t)(b0 + q) * 768 + c;
      gr = g0[0]; gz = g0[256]; gn = g0[512];
    }
    if (tid < 576) hbuf[tid] = (f16)0.f;
    __syncthreads();
    for (int t = 0; t < 50; t++) {
      float s[2][3] = {};
      #pragma unroll
      for (int m = 0; m < 8; m++) {
        #pragma unroll
        for (int qq = 0; qq < 2; qq++) {
          i32x4 hw = *(const i32x4*)(hbuf + qq * 288 + chunk * 72 + m * 8);
          #pragma unroll
          for (int p = 0; p < 4; p++) {
            f16x2 hp = __builtin_bit_cast(f16x2, hw[p]);
            s[qq][0] = fdot2(hp, __builtin_bit_cast(f16x2, Wv[0][m][p]), s[qq][0]);
            s[qq][1] = fdot2(hp, __builtin_bit_cast(f16x2, Wv[1][m][p]), s[qq][1]);
            s[qq][2] = fdot2(hp, __builtin_bit_cast(f16x2, Wv[2][m][p]), s[qq][2]);
          }
        }
      }
      #pragma unroll
      for (int qq = 0; qq < 2; qq++)
        #pragma unroll
        for (int j = 0; j < 3; j++) {
          s[qq][j] += __shfl_xor(s[qq][j], 16);
          s[qq][j] += __shfl_xor(s[qq][j], 32);
        }
      if (l < 16) {
        #pragma unroll
        for (int qq = 0; qq < 2; qq++) {
          ghbuf[qq * 768 + w * 48 + l]      = s[qq][0];
          ghbuf[qq * 768 + w * 48 + 16 + l] = s[qq][1];
          ghbuf[qq * 768 + w * 48 + 32 + l] = s[qq][2];
        }
      }
      __syncthreads();
      if (tid < 512) {
        float rg = sigm((float)gr + ghbuf[q * 768 + c]);
        float zg = sigm((float)gz + ghbuf[q * 768 + 256 + c]);
        float ng = tanh_fast((float)gn + rg * (ghbuf[q * 768 + 512 + c] + bN));
        float hv = ng + zg * (hprev - ng);
        hprev = hv;
        hbuf[q * 288 + (c >> 6) * 72 + (c & 63)] = (f16)hv;
        y_all[((size_t)t * 256 + b0 + q) * 256 + c] = (f16)hv;
        if (t < 49) {
          const f16* gN = gi + ((size_t)(t + 1) * 256 + b0 + q) * 768 + c;
          gr = gN[0]; gz = gN[256]; gn = gN[512];
        }
      }
      __syncthreads();
    }
  } else if (blockIdx.x < 152) {
    // ---------------- MN trajectory (grid-strided) ----------------
    int lane = l;
    for (int pair = (blockIdx.x - 128) * 16 + w; pair < 2560; pair += 384) {
      int b = pair / 10, f = pair - (pair / 10) * 10;
      float r0_ = Rm[f * 128 + lane], r1_ = Rm[f * 128 + 64 + lane];
      float mn0 = 0.f, mn1 = 0.f;
      float c0 = (float)tv[(size_t)b * 128 + lane];
      float c1 = (float)tv[(size_t)b * 128 + 64 + lane];
      for (int t = 0; t < 50; t++) {
        float ea0 = c0 + r0_;
        float ea1 = c1 + r1_;
        if (t < 49) {
          size_t nb = ((size_t)(t + 1) * 256 + b) * 128;
          c0 = (float)tv[nb + lane];
          c1 = (float)tv[nb + 64 + lane];
        }
        float p = mn0 * ea0 + mn1 * ea1;
        #pragma unroll
        for (int off = 32; off > 0; off >>= 1) p += __shfl_xor(p, off);
        float g = sigm(p);
        mn0 += (ea0 - mn0) * g;
        mn1 += (ea1 - mn1) * g;
        size_t mb = (((size_t)t * 256 + b) * 10 + f) * 128;
        MN[mb + lane] = (f16)mn0;
        MN[mb + 64 + lane] = (f16)mn1;
      }
    }
  } else {
    // ---------------- persistent Sy (grid-strided, 16 waves) ----------------
    f16* At = (f16*)smem;                      // [32][392]
    int lane = l, lr = lane & 15, lg = lane >> 4;
    int mt = w & 1, ntp = w >> 1;
    for (int tile = blockIdx.x - 152; tile < 3125; tile += 104) {
      int i0 = tile * 32;
      {
        int r = tid >> 5;
        int item = i0 + r;
        int c = (tid & 31) * 8;                // E part
        if (item == 0) {
          #pragma unroll
          for (int j = 0; j < 8; j++) At[r * 392 + c + j] = (f16)0.f;
        } else {
          const float4* sp = (const float4*)(E + (size_t)item * 256 + c);
          #pragma unroll
          for (int qq = 0; qq < 2; qq++) {
            float4 v = sp[qq];
            At[r * 392 + c + qq*4 + 0] = (f16)v.x; At[r * 392 + c + qq*4 + 1] = (f16)v.y;
            At[r * 392 + c + qq*4 + 2] = (f16)v.z; At[r * 392 + c + qq*4 + 3] = (f16)v.w;
          }
        }
        int c2 = (tid & 31) * 4;               // KBE part
        if (item == 0) {
          #pragma unroll
          for (int j = 0; j < 4; j++) At[r * 392 + 256 + c2 + j] = (f16)0.f;
        } else {
          float4 v = *(const float4*)(KBE + (size_t)item * 128 + c2);
          At[r * 392 + 256 + c2 + 0] = (f16)v.x; At[r * 392 + 256 + c2 + 1] = (f16)v.y;
          At[r * 392 + 256 + c2 + 2] = (f16)v.z; At[r * 392 + 256 + c2 + 3] = (f16)v.w;
        }
      }
      __syncthreads();
      f32x4 acc[2] = {};
      for (int ks = 0; ks < 12; ks++) {
        f16x8 a = *(const f16x8*)(&At[(mt * 16 + lr) * 392 + ks * 32 + lg * 8]);
        #pragma unroll
        for (int j = 0; j < 2; j++) {
          int nt = ntp * 2 + j;
          f16x8 bf = *(const f16x8*)(mlp2_p + ((size_t)((nt * 12 + ks) * 64 + lane) << 3));
          acc[j] = MFMA16(a, bf, acc[j]);
        }
      }
      #pragma unroll
      for (int j = 0; j < 2; j++) {
        int col = (ntp * 2 + j) * 16 + lr;
        float bias = mlp2b[col];
        #pragma unroll
        for (int rr = 0; rr < 4; rr++) {
          int item = i0 + mt * 16 + lg * 4 + rr;
          Sy[(size_t)item * 256 + col] = (f16)tanh_fast(acc[j][rr] + bias);
        }
      }
      __syncthreads();
    }
  }
}

// ============================================================================
// Per-(t,b) epilogue (16 rows/block, no atomics):
//  U = tanh(y@MNu.T+b); AW = softmax(U@r.T); AC = sum_f AW*MN;
//  Ut = tanh([y|AC]@MNu2.T+b); ypart = tanh(Ut@mlp1.T+b)
// ============================================================================
__global__ __launch_bounds__(512) void k_uacut(
    const f16* __restrict__ y_all, const f16* __restrict__ MNu_p,
    const float* __restrict__ MNub, const float* __restrict__ Rm,
    const f16* __restrict__ MN,
    const f16* __restrict__ MNu2_p, const float* __restrict__ MNu2b,
    const f16* __restrict__ mlp1_p, const float* __restrict__ mlp1b,
    float* __restrict__ ypart)
{
  __shared__ __align__(16) char smem[25088];
  int tid = threadIdx.x, w = tid >> 6, lane = tid & 63, lr = lane & 15, lg = lane >> 4;
  f16   (*Aty)[264] = (f16(*)[264])smem;
  float (*Uf)[136]  = (float(*)[136])(smem + 8448);
  f16   (*Utl)[264] = (f16(*)[264])(smem + 8448);
  float (*Lg)[10]   = (float(*)[10])(smem + 17152);
  float (*Aw)[10]   = (float(*)[10])(smem + 17792);
  f16   (*ACs)[136] = (f16(*)[136])(smem + 18432);
  int r0 = blockIdx.x * 16;
  {
    int r = tid >> 5, c = (tid & 31) * 8;
    f16x8 v = *(const f16x8*)(y_all + (size_t)(r0 + r) * 256 + c);
    *(f16x8*)(&Aty[r][c]) = v;
  }
  __syncthreads();
  {
    f32x4 acc = {};
    for (int ks = 0; ks < 8; ks++) {
      f16x8 a = *(const f16x8*)(&Aty[lr][ks * 32 + lg * 8]);
      f16x8 bf = *(const f16x8*)(MNu_p + ((size_t)((w * 8 + ks) * 64 + lane) << 3));
      acc = MFMA16(a, bf, acc);
    }
    int col = w * 16 + lr;
    float bias = MNub[col];
    #pragma unroll
    for (int rr = 0; rr < 4; rr++)
      Uf[lg * 4 + rr][col] = tanh_fast(acc[rr] + bias);
  }
  __syncthreads();
  if (tid < 160) {
    int row = tid / 10, f = tid - (tid / 10) * 10;
    float s = 0.f;
    for (int d = 0; d < 128; d++) s += Uf[row][d] * Rm[f * 128 + d];
    Lg[row][f] = s;
  }
  __syncthreads();
  if (tid < 16) {
    float m = -1e30f;
    #pragma unroll
    for (int f = 0; f < 10; f++) m = fmaxf(m, Lg[tid][f]);
    float e[10], s = 0.f;
    #pragma unroll
    for (int f = 0; f < 10; f++) { e[f] = __expf(Lg[tid][f] - m); s += e[f]; }
    float inv = 1.f / s;
    #pragma unroll
    for (int f = 0; f < 10; f++) Aw[tid][f] = e[f] * inv;
  }
  __syncthreads();
  if (tid < 256) {
    int row = tid >> 4, d0 = (tid & 15) * 8;
    float a[8] = {0,0,0,0,0,0,0,0};
    for (int f = 0; f < 10; f++) {
      float wgt = Aw[row][f];
      f16x8 mv = *(const f16x8*)(MN + (((size_t)(r0 + row)) * 10 + f) * 128 + d0);
      #pragma unroll
      for (int q = 0; q < 8; q++) a[q] += wgt * (float)mv[q];
    }
    f16x8 o;
    #pragma unroll
    for (int q = 0; q < 8; q++) o[q] = (f16)a[q];
    *(f16x8*)(&ACs[row][d0]) = o;
  }
  __syncthreads();
  {
    f32x4 acc[2] = {};
    for (int ks = 0; ks < 12; ks++) {
      f16x8 a = (ks < 8)
        ? *(const f16x8*)(&Aty[lr][ks * 32 + lg * 8])
        : *(const f16x8*)(&ACs[lr][(ks - 8) * 32 + lg * 8]);
      #pragma unroll
      for (int j = 0; j < 2; j++) {
        f16x8 bf = *(const f16x8*)(MNu2_p + ((size_t)(((w * 2 + j) * 12 + ks) * 64 + lane) << 3));
        acc[j] = MFMA16(a, bf, acc[j]);
      }
    }
    __syncthreads();   // Uf (overlaid) fully dead before Utl writes
    #pragma unroll
    for (int j = 0; j < 2; j++) {
      int col = (w * 2 + j) * 16 + lr;
      float bias = MNu2b[col];
      #pragma unroll
      for (int rr = 0; rr < 4; rr++)
        Utl[lg * 4 + rr][col] = (f16)tanh_fast(acc[j][rr] + bias);
    }
  }
  __syncthreads();
  {
    f32x4 acc2[2] = {};
    for (int ks = 0; ks < 8; ks++) {
      f16x8 a = *(const f16x8*)(&Utl[lr][ks * 32 + lg * 8]);
      #pragma unroll
      for (int j = 0; j < 2; j++) {
        f16x8 bf = *(const f16x8*)(mlp1_p + ((size_t)(((w * 2 + j) * 8 + ks) * 64 + lane) << 3));
        acc2[j] = MFMA16(a, bf, acc2[j]);
      }
    }
    #pragma unroll
    for (int j = 0; j < 2; j++) {
      int col = (w * 2 + j) * 16 + lr;
      float bias = mlp1b[col];
      #pragma unroll
      for (int rr = 0; rr < 4; rr++) {
        int row = r0 + lg * 4 + rr;
        ypart[(size_t)row * 256 + col] = tanh_fast(acc2[j][rr] + bias);
      }
    }
  }
}

// y[b][c] = (1/50) * sum_t ypart[t*256+b][c] -> d_out tail (f32) + f16 copy
__global__ __launch_bounds__(256) void k_yfin(
    const float* __restrict__ ypart, float* __restrict__ outy, f16* __restrict__ y16)
{
  int b = blockIdx.x, c = threadIdx.x;
  float s = 0.f;
  for (int t = 0; t < 50; t++) s += ypart[((size_t)t * 256 + b) * 256 + c];
  float v = s * (1.0f / 50.0f);
  outy[b * 256 + c] = v;
  y16[b * 256 + c] = (f16)v;
}

// ============================================================================
// SINGLE scores GEMM: raw f16 scores (dead workspace span) + (max,sumexp).
// ============================================================================
__global__ __launch_bounds__(512) void k_scoreraw(
    const f16* __restrict__ y16, const f16* __restrict__ Sy,
    float* __restrict__ pmax, float* __restrict__ psum, f16* __restrict__ raw)
{
  __shared__ float pm[512], ps[512];
  int tid = threadIdx.x, w = tid >> 6, lane = tid & 63, lr = lane & 15, lg = lane >> 4;
  int i0 = blockIdx.x * 64;
  int mtb = (w >> 1) * 4, ntb = (w & 1) * 2;
  f32x4 acc[4][2] = {};
  for (int ks = 0; ks < 8; ks++) {
    f16x8 a[4];
    #pragma unroll
    for (int i = 0; i < 4; i++)
      a[i] = *(const f16x8*)(y16 + ((size_t)((mtb + i) * 16 + lr)) * 256 + ks * 32 + lg * 8);
    #pragma unroll
    for (int j = 0; j < 2; j++) {
      int item = i0 + (ntb + j) * 16 + lr;
      int ic = item < NITEMS ? item : (NITEMS - 1);
      f16x8 bv = *(const f16x8*)(Sy + (size_t)ic * 256 + ks * 32 + lg * 8);
      #pragma unroll
      for (int i = 0; i < 4; i++) acc[i][j] = MFMA16(a[i], bv, acc[i][j]);
    }
  }
  #pragma unroll
  for (int i = 0; i < 4; i++)
    #pragma unroll
    for (int j = 0; j < 2; j++) {
      int c = i0 + (ntb + j) * 16 + lr;
      if (c < NITEMS) {
        #pragma unroll
        for (int rr = 0; rr < 4; rr++) {
          int row = (mtb + i) * 16 + lg * 4 + rr;
          raw[(size_t)row * NITEMS + c] = (f16)acc[i][j][rr];
        }
      }
    }
  {
    int item0 = i0 + ntb * 16 + lr, item1 = item0 + 16;
    bool v0 = item0 < NITEMS, v1 = item1 < NITEMS;
    #pragma unroll
    for (int i = 0; i < 4; i++)
      #pragma unroll
      for (int rr = 0; rr < 4; rr++) {
        float x0 = v0 ? acc[i][0][rr] : -1e30f;
        float x1 = v1 ? acc[i][1][rr] : -1e30f;
        float m = fmaxf(x0, x1);
        m = fmaxf(m, __shfl_xor(m, 1)); m = fmaxf(m, __shfl_xor(m, 2));
        m = fmaxf(m, __shfl_xor(m, 4)); m = fmaxf(m, __shfl_xor(m, 8));
        float s = (v0 ? __expf(x0 - m) : 0.f) + (v1 ? __expf(x1 - m) : 0.f);
        s += __shfl_xor(s, 1); s += __shfl_xor(s, 2);
        s += __shfl_xor(s, 4); s += __shfl_xor(s, 8);
        if (lr == 0) {
          int row = (mtb + i) * 16 + lg * 4 + rr;
          pm[(w & 1) * 256 + row] = m;
          ps[(w & 1) * 256 + row] = s;
        }
      }
  }
  __syncthreads();
  if (tid < 256) {
    float m0 = pm[tid], m1 = pm[256 + tid];
    float s0 = ps[tid], s1 = ps[256 + tid];
    float M = fmaxf(m0, m1);
    float S = s0 * __expf(m0 - M) + s1 * __expf(m1 - M);
    pmax[(size_t)tid * 1600 + blockIdx.x] = M;
    psum[(size_t)tid * 1600 + blockIdx.x] = S;
  }
}

// combine per-block partials -> lse[b]
__global__ __launch_bounds__(256) void k_lse(
    const float* __restrict__ pmax, const float* __restrict__ psum, float* __restrict__ lse)
{
  int b = blockIdx.x, tid = threadIdx.x;
  __shared__ float red[256];
  float m = -1e30f;
  for (int i = tid; i < NBLK4; i += 256) m = fmaxf(m, pmax[(size_t)b * 1600 + i]);
  red[tid] = m; __syncthreads();
  for (int s = 128; s > 0; s >>= 1) {
    if (tid < s) red[tid] = fmaxf(red[tid], red[tid + s]);
    __syncthreads();
  }
  float M = red[0]; __syncthreads();
  float s = 0.f;
  for (int i = tid; i < NBLK4; i += 256)
    s += psum[(size_t)b * 1600 + i] * __expf(pmax[(size_t)b * 1600 + i] - M);
  red[tid] = s; __syncthreads();
  for (int q = 128; q > 0; q >>= 1) {
    if (tid < q) red[tid] += red[tid + q];
    __syncthreads();
  }
  if (tid == 0) lse[b] = M + logf(red[0]);
}

// ============================================================================
// fix pass: out[row][c] = f32(raw[row][c]) - lse[row]
// ============================================================================
__global__ __launch_bounds__(256) void k_fix(
    const f16* __restrict__ raw, const float* __restrict__ lse, float* __restrict__ out)
{
  int row = blockIdx.y;
  int idx = blockIdx.x * 256 + threadIdx.x;      // f16x8 units; 12500 per row
  if (idx < 12500) {
    float l = lse[row];
    f16x8 v = *(const f16x8*)(raw + (size_t)row * NITEMS + idx * 8);
    float4 o0, o1;
    o0.x = (float)v[0] - l; o0.y = (float)v[1] - l;
    o0.z = (float)v[2] - l; o0.w = (float)v[3] - l;
    o1.x = (float)v[4] - l; o1.y = (float)v[5] - l;
    o1.z = (float)v[6] - l; o1.w = (float)v[7] - l;
    float4* p = (float4*)(out + (size_t)row * NITEMS + idx * 8);
    p[0] = o0; p[1] = o1;
  }
}

// ============================================================================
extern "C" void kernel_launch(void* const* d_in, const int* in_sizes, int n_in,
                              void* d_out, int out_size, void* d_ws, size_t ws_size,
                              hipStream_t stream) {
  (void)in_sizes; (void)n_in; (void)out_size; (void)ws_size;
  const int*   X     = (const int*)d_in[0];
  const float* E     = (const float*)d_in[1];
  const float* KBE   = (const float*)d_in[2];
  const float* Rm    = (const float*)d_in[3];
  const float* Wih   = (const float*)d_in[4];
  const float* Whh   = (const float*)d_in[5];
  const float* bih   = (const float*)d_in[6];
  const float* bhh   = (const float*)d_in[7];
  const float* MNuW  = (const float*)d_in[8];
  const float* MNub  = (const float*)d_in[9];
  const float* MNu2W = (const float*)d_in[10];
  const float* MNu2b = (const float*)d_in[11];
  const float* MNeaW = (const float*)d_in[12];
  const float* MNeab = (const float*)d_in[13];
  const float* mlp1W = (const float*)d_in[14];
  const float* mlp1b = (const float*)d_in[15];
  const float* mlp2W = (const float*)d_in[16];
  const float* mlp2b = (const float*)d_in[17];

  char* ws = (char*)d_ws;
  f16*   Wih_p  = (f16*)(ws + OFF_WIH);
  f16*   MNu_p  = (f16*)(ws + OFF_MNU);
  f16*   MNu2_p = (f16*)(ws + OFF_MNU2);
  f16*   Wea_p  = (f16*)(ws + OFF_MNEA);
  f16*   mlp1_p = (f16*)(ws + OFF_MLP1);
  f16*   mlp2_p = (f16*)(ws + OFF_MLP2);
  f16*   Whh_d  = (f16*)(ws + OFF_WHHD);
  f16*   gi     = (f16*)(ws + OFF_GI);
  f16*   tv     = (f16*)(ws + OFF_TV);
  f16*   MN     = (f16*)(ws + OFF_MN);
  f16*   y_all  = (f16*)(ws + OFF_YALL);
  f16*   Sy     = (f16*)(ws + OFF_SY);
  float* ypart  = (float*)(ws + OFF_GI);   // reuse gi region (scan is done)
  f16*   raw    = (f16*)(ws + OFF_GI);     // raw f16 scores (after yfin; 51.2MB)
  f16*   y16    = (f16*)(ws + OFF_Y16);
  float* pmax   = (float*)(ws + OFF_PMAX);
  float* psum   = (float*)(ws + OFF_PSUM);
  float* lse    = (float*)(ws + OFF_LSE);
  float* outf   = (float*)d_out;

  k_pack<<<440, 256, 0, stream>>>(Wih, Whh, MNuW, MNu2W, MNeaW, mlp1W, mlp2W, (f16*)ws);
  k_prep<<<800, 512, 0, stream>>>(X, E, Wih_p, bih, bhh, gi, KBE, Wea_p, MNeab, tv);
  k_fused4<<<256, 1024, 0, stream>>>(Whh_d, bhh, gi, y_all, tv, Rm, MN,
                                     E, KBE, mlp2_p, mlp2b, Sy);
  k_uacut<<<800, 512, 0, stream>>>(y_all, MNu_p, MNub, Rm, MN,
                                   MNu2_p, MNu2b, mlp1_p, mlp1b, ypart);
  k_yfin<<<256, 256, 0, stream>>>(ypart, outf + 25600000, y16);
  k_scoreraw<<<NBLK4, 512, 0, stream>>>(y16, Sy, pmax, psum, raw);
  k_lse<<<256, 256, 0, stream>>>(pmax, psum, lse);
  dim3 gfix(49, 256);
  k_fix<<<gfix, 256, 0, stream>>>(raw, lse, outf);
}

// Round 18
// 319.808 us; speedup vs baseline: 1.1008x; 1.1008x over previous
//
#include <hip/hip_runtime.h>

typedef _Float16 f16;
typedef _Float16 f16x4 __attribute__((ext_vector_type(4)));
typedef _Float16 f16x8 __attribute__((ext_vector_type(8)));
typedef float f32x4 __attribute__((ext_vector_type(4)));

#define MFMA16(a,b,c) __builtin_amdgcn_mfma_f32_16x16x32_f16(a,b,c,0,0,0)

#define NITEMS 100000
#define NBLK4  1563   // ceil(100000/64)

// ---- workspace byte offsets ----
#define OFF_WIH   0u
#define OFF_WHH   393216u
#define OFF_MNU   786432u
#define OFF_MNU2  851968u
#define OFF_MNEA  1048576u
#define OFF_MLP1  1081344u
#define OFF_MLP2  1212416u
#define OFF_GI    1409024u          // gi2 lane-packed; later ypart; later raw f16 scores
#define OFF_TV    21069824u         // 12800x128 f16
#define OFF_MN    24346624u         // 50x256x10x128 f16
#define OFF_YALL  57114624u         // 12800x256 f16
#define OFF_SY    66945024u         // 100000x256 f16
#define OFF_Y16   118407168u        // 256x256 f16
#define OFF_PMAX  118538240u        // 256x1600 f32
#define OFF_PSUM  120176640u        // 256x1600 f32
#define OFF_LSE   121815040u        // 256 f32

__device__ __forceinline__ float sigm(float x) { return 1.f / (1.f + __expf(-x)); }
__device__ __forceinline__ float tanh_fast(float x) {
  return 1.f - 2.f / (1.f + __expf(2.f * x));
}

// ============================================================================
// Pack all weight matrices (x @ W.T form) into f16 MFMA B-fragment streams.
// ============================================================================
__global__ __launch_bounds__(256) void k_pack(
    const float* s0, const float* s1, const float* s2, const float* s3,
    const float* s4, const float* s5, const float* s6, f16* base)
{
  int fid = blockIdx.x * 256 + threadIdx.x;  // 88064 total
  const float* src; f16* dst; int K, f;
  if (fid < 24576)      { src = s0; dst = base;          K = 256; f = fid; }          // W_ih 768x256
  else if (fid < 49152) { src = s1; dst = base + 196608; K = 256; f = fid - 24576; }  // W_hh 768x256
  else if (fid < 53248) { src = s2; dst = base + 393216; K = 256; f = fid - 49152; }  // MNu_W 128x256
  else if (fid < 65536) { src = s3; dst = base + 425984; K = 384; f = fid - 53248; }  // MNu2_W 256x384
  else if (fid < 67584) { src = s4; dst = base + 524288; K = 128; f = fid - 65536; }  // MNea_W 128x128
  else if (fid < 75776) { src = s5; dst = base + 540672; K = 256; f = fid - 67584; }  // mlp1_W 256x256
  else                  { src = s6; dst = base + 606208; K = 384; f = fid - 75776; }  // mlp2_W 256x384
  int lane = f & 63, t2 = f >> 6, KS = K >> 5;
  int ks = t2 % KS, nt = t2 / KS;
  int row = nt * 16 + (lane & 15), col = ks * 32 + ((lane >> 4) << 3);
  const float* sp = src + (size_t)row * K + col;
  f16x8 v;
  #pragma unroll
  for (int j = 0; j < 8; j++) v[j] = (f16)sp[j];
  *(f16x8*)(dst + (size_t)f * 8) = v;
}

// ============================================================================
//  blocks 0..399    gi2 = lane-packed (E[X] @ W_ih.T + bih [+ bhh for r,z])
//                   layout: [t][grp(32)][wave(16)][lane(32)][12] f16
//  blocks 400..799  tv = f16(tanh(KBE[X] @ MNea_W.T + b)), LDS-staged writes
// ============================================================================
__global__ __launch_bounds__(512) void k_giea(
    const int* __restrict__ X, const float* __restrict__ E,
    const f16* __restrict__ Wih_p, const float* __restrict__ bih,
    const float* __restrict__ bhh, f16* __restrict__ gi2,
    const float* __restrict__ KBE, const f16* __restrict__ Wea_p,
    const float* __restrict__ bea, f16* __restrict__ tv)
{
  __shared__ __align__(16) char smem[66048];   // At 16896 | Lg2 49152
  f16 (*At)[264] = (f16(*)[264])smem;
  f16* Lg2 = (f16*)(smem + 16896);
  int tid = threadIdx.x;
  int w = tid >> 6, lane = tid & 63, lr = lane & 15, lg = lane >> 4;
  if (blockIdx.x < 400) {
    int r0g = blockIdx.x * 32;        // global row (t*256 + b); one t per block
    int t = r0g >> 8;
    int grp0 = (r0g & 255) >> 3;      // first of 4 scan groups covered
    { // stage A-tile (32 rows x 256 K, f32 -> f16), gather with row-0 masking
      int r = tid >> 4, c = (tid & 15) * 16;
      int b = (r0g + r) & 255;
      int item = X[b * 50 + t];
      if (item == 0) {
        #pragma unroll
        for (int j = 0; j < 16; j++) At[r][c + j] = (f16)0.f;
      } else {
        const float4* sp = (const float4*)(E + (size_t)item * 256 + c);
        #pragma unroll
        for (int q = 0; q < 4; q++) {
          float4 v = sp[q];
          At[r][c + q*4 + 0] = (f16)v.x; At[r][c + q*4 + 1] = (f16)v.y;
          At[r][c + q*4 + 2] = (f16)v.z; At[r][c + q*4 + 3] = (f16)v.w;
        }
      }
    }
    __syncthreads();
    f32x4 acc[2][6] = {};
    for (int ks = 0; ks < 8; ks++) {
      f16x8 a0 = *(const f16x8*)(&At[lr][ks * 32 + lg * 8]);
      f16x8 a1 = *(const f16x8*)(&At[16 + lr][ks * 32 + lg * 8]);
      #pragma unroll
      for (int j = 0; j < 6; j++) {
        int nt = w * 6 + j;
        f16x8 bf = *(const f16x8*)(Wih_p + ((size_t)((nt * 8 + ks) * 64 + lane) << 3));
        acc[0][j] = MFMA16(a0, bf, acc[0][j]);
        acc[1][j] = MFMA16(a1, bf, acc[1][j]);
      }
    }
    // scatter into the lane-packed staging buffer:
    // Lg2[grp_local(4)][w_s(16)][lane_s(32)][12: gate*4+rr]
    int lane_s = ((lg & 1) << 4) | lr;
    #pragma unroll
    for (int j = 0; j < 6; j++) {
      int tile = w * 6 + j;
      int gate = tile >> 4, w_s = tile & 15;
      int col = tile * 16 + lr;
      float bias = bih[col] + (col < 512 ? bhh[col] : 0.f);
      #pragma unroll
      for (int mt = 0; mt < 2; mt++) {
        int grp_local = mt * 2 + (lg >> 1);
        f16* dstp = Lg2 + (((grp_local * 16 + w_s) * 32 + lane_s) * 12 + gate * 4);
        #pragma unroll
        for (int rr = 0; rr < 4; rr++)
          dstp[rr] = (f16)(acc[mt][j][rr] + bias);
      }
    }
    __syncthreads();
    // coalesced copy-out: 4 groups x 6144 f16 = 3072 f16x8 units
    f16* dst = gi2 + ((size_t)t * 32 + grp0) * 6144;
    #pragma unroll
    for (int q = 0; q < 6; q++) {
      int i = q * 512 + tid;
      *(f16x8*)(dst + i * 8) = *(const f16x8*)(Lg2 + i * 8);
    }
  } else {
    int r0 = (blockIdx.x - 400) * 32;
    int t = r0 >> 8;
    {
      int r = tid >> 4, c = (tid & 15) * 8;
      int b = (r0 + r) & 255;
      int item = X[b * 50 + t];
      if (item == 0) {
        #pragma unroll
        for (int j = 0; j < 8; j++) At[r][c + j] = (f16)0.f;
      } else {
        const float4* sp = (const float4*)(KBE + (size_t)item * 128 + c);
        #pragma unroll
        for (int q = 0; q < 2; q++) {
          float4 v = sp[q];
          At[r][c + q*4 + 0] = (f16)v.x; At[r][c + q*4 + 1] = (f16)v.y;
          At[r][c + q*4 + 2] = (f16)v.z; At[r][c + q*4 + 3] = (f16)v.w;
        }
      }
    }
    __syncthreads();
    f32x4 acc[2] = {};
    for (int ks = 0; ks < 4; ks++) {
      f16x8 a0 = *(const f16x8*)(&At[lr][ks * 32 + lg * 8]);
      f16x8 a1 = *(const f16x8*)(&At[16 + lr][ks * 32 + lg * 8]);
      f16x8 bf = *(const f16x8*)(Wea_p + ((size_t)((w * 4 + ks) * 64 + lane) << 3));
      acc[0] = MFMA16(a0, bf, acc[0]);
      acc[1] = MFMA16(a1, bf, acc[1]);
    }
    // stage tv tile in LDS (Lg2 region), then coalesce out
    f16* tvs = Lg2;                    // [32][128] f16
    int col = w * 16 + lr;
    float bias = bea[col];
    #pragma unroll
    for (int mt = 0; mt < 2; mt++)
      #pragma unroll
      for (int rr = 0; rr < 4; rr++)
        tvs[(mt * 16 + lg * 4 + rr) * 128 + col] = (f16)tanh_fast(acc[mt][rr] + bias);
    __syncthreads();
    {
      int row = tid >> 4, c = (tid & 15) * 8;
      *(f16x8*)(tv + (size_t)(r0 + row) * 128 + c) = *(const f16x8*)(tvs + row * 128 + c);
    }
  }
}

// ============================================================================
//  blocks 0..31    persistent GRU scan, 8 rows each, 16 waves.
//                  r-gate W in LDS (131KB); z/n tiles stream from L2;
//                  gi2 lane-packed reads (24B contiguous per lane).
//  blocks 32..191  MN trajectory (one wave per (b,f) pair)
//  blocks 192..3316 Sy = tanh([E|KBE] @ mlp2.T + b), 16-wave variant
// ============================================================================
__global__ __launch_bounds__(1024)
__attribute__((amdgpu_waves_per_eu(4, 4)))
void k_fused(
    const f16* __restrict__ Whh_p, const float* __restrict__ bhh,
    const f16* __restrict__ gi2, f16* __restrict__ y_all,
    const f16* __restrict__ tv, const float* __restrict__ Rm, f16* __restrict__ MN,
    const float* __restrict__ E, const float* __restrict__ KBE,
    const f16* __restrict__ mlp2_p, const float* __restrict__ mlp2b, f16* __restrict__ Sy)
{
  __shared__ __align__(16) char smem[147456];
  int tid = threadIdx.x, w = tid >> 6, lane = tid & 63, lr = lane & 15, lg = lane >> 4;

  if (blockIdx.x < 32) {
    // ---------------- GRU scan (8 rows/block) ----------------
    f16* Wlds = (f16*)smem;            // r-gate tiles 0..15: 131072 B
    f16* hb0 = (f16*)(smem + 131072);  // [16][256] f16 swizzled; rows 8..15 stay 0
    f16* hb1 = (f16*)(smem + 139264);
    int r0 = blockIdx.x * 8;
    {
      const float4* src = (const float4*)Whh_p;
      float4* dst = (float4*)Wlds;
      #pragma unroll
      for (int i = 0; i < 8; i++) dst[tid + i * 1024] = src[tid + i * 1024];
      float4 z4 = {0.f, 0.f, 0.f, 0.f};
      ((float4*)hb0)[tid] = z4;        // 1024 x 16B = 16 KB covers hb0 AND hb1
    }
    int col = w * 16 + lr;
    float bN = bhh[col + 512];
    float hreg[4] = {0.f, 0.f, 0.f, 0.f};
    const f16* gP = gi2 + (size_t)blockIdx.x * 6144 + (size_t)(w * 32 + lane) * 12;
    f16x8 P0 = {};
    f16x4 P1 = {};
    if (lg < 2) {
      P0 = *(const f16x8*)gP;
      P1 = *(const f16x4*)(gP + 8);
    }
    __syncthreads();
    f16* hc = hb0; f16* hn_ = hb1;
    int xr = (lr & 7) << 4;
    const f16* wB0 = Wlds + (size_t)w * 4096 + lane * 8;
    const f16* wBz = Whh_p + ((size_t)((16 + w) * 8) * 64 + lane) * 8;
    const f16* wBn = Whh_p + ((size_t)((32 + w) * 8) * 64 + lane) * 8;
    for (int t = 0; t < 50; t++) {
      f32x4 aR = {}, aZ = {}, aN = {};
      const char* hbase = (const char*)hc + lr * 512;
      #pragma unroll
      for (int ks = 0; ks < 8; ks++) {
        f16x8 a = *(const f16x8*)(hbase + ((ks * 64 + lg * 16) ^ xr));
        aR = MFMA16(a, *(const f16x8*)(wB0 + ks * 512), aR);
        aZ = MFMA16(a, *(const f16x8*)(wBz + ks * 512), aZ);
        aN = MFMA16(a, *(const f16x8*)(wBn + ks * 512), aN);
      }
      if (lg < 2) {
        #pragma unroll
        for (int rr = 0; rr < 4; rr++) {
          int row = lg * 4 + rr;                     // 0..7
          float rg = sigm((float)P0[rr] + aR[rr]);
          float zg = sigm((float)P0[4 + rr] + aZ[rr]);
          float ng = tanh_fast((float)P1[rr] + rg * (aN[rr] + bN));
          float hv = ng + zg * (hreg[rr] - ng);
          hreg[rr] = hv;
          *(f16*)((char*)hn_ + row * 512 + ((col * 2) ^ ((row & 7) << 4))) = (f16)hv;
        }
        if (t < 49) {
          const f16* gN = gP + (size_t)(t + 1) * 196608;   // 32 grps * 6144
          P0 = *(const f16x8*)gN;
          P1 = *(const f16x4*)(gN + 8);
        }
      }
      __syncthreads();
      // vectorized y_all store from the just-written h buffer
      if (tid < 256) {
        int row = tid >> 5, c = tid & 31;
        f16x8 hv = *(const f16x8*)((char*)hn_ + row * 512 + ((c * 16) ^ ((row & 7) << 4)));
        *(f16x8*)(y_all + ((size_t)t * 256 + r0 + row) * 256 + c * 8) = hv;
      }
      f16* tmp = hc; hc = hn_; hn_ = tmp;
    }
  } else if (blockIdx.x < 192) {
    // ---------------- MN trajectory ----------------
    int pair = (blockIdx.x - 32) * 16 + w;   // 2560 pairs
    int b = pair / 10, f = pair - (pair / 10) * 10;
    float r0_ = Rm[f * 128 + lane], r1_ = Rm[f * 128 + 64 + lane];
    float mn0 = 0.f, mn1 = 0.f;
    float c0 = (float)tv[(size_t)b * 128 + lane];
    float c1 = (float)tv[(size_t)b * 128 + 64 + lane];
    for (int t = 0; t < 50; t++) {
      float ea0 = c0 + r0_;
      float ea1 = c1 + r1_;
      if (t < 49) {
        size_t nb = ((size_t)(t + 1) * 256 + b) * 128;
        c0 = (float)tv[nb + lane];
        c1 = (float)tv[nb + 64 + lane];
      }
      float p = mn0 * ea0 + mn1 * ea1;
      #pragma unroll
      for (int off = 32; off > 0; off >>= 1) p += __shfl_xor(p, off);
      float g = sigm(p);
      mn0 += (ea0 - mn0) * g;
      mn1 += (ea1 - mn1) * g;
      size_t mb = (((size_t)t * 256 + b) * 10 + f) * 128;
      MN[mb + lane] = (f16)mn0;
      MN[mb + 64 + lane] = (f16)mn1;
    }
  } else {
    // ---------------- Sy (16-wave variant) ----------------
    f16* At = (f16*)smem;                      // [32][392]
    int i0 = (blockIdx.x - 192) * 32;
    {
      int r = tid >> 5;
      int item = i0 + r;
      int c = (tid & 31) * 8;                  // E part: 8 f32 each
      if (item == 0) {
        #pragma unroll
        for (int j = 0; j < 8; j++) At[r * 392 + c + j] = (f16)0.f;
      } else {
        const float4* sp = (const float4*)(E + (size_t)item * 256 + c);
        #pragma unroll
        for (int q = 0; q < 2; q++) {
          float4 v = sp[q];
          At[r * 392 + c + q*4 + 0] = (f16)v.x; At[r * 392 + c + q*4 + 1] = (f16)v.y;
          At[r * 392 + c + q*4 + 2] = (f16)v.z; At[r * 392 + c + q*4 + 3] = (f16)v.w;
        }
      }
      int c2 = (tid & 31) * 4;                 // KBE part: 4 f32 each
      if (item == 0) {
        #pragma unroll
        for (int j = 0; j < 4; j++) At[r * 392 + 256 + c2 + j] = (f16)0.f;
      } else {
        float4 v = *(const float4*)(KBE + (size_t)item * 128 + c2);
        At[r * 392 + 256 + c2 + 0] = (f16)v.x; At[r * 392 + 256 + c2 + 1] = (f16)v.y;
        At[r * 392 + 256 + c2 + 2] = (f16)v.z; At[r * 392 + 256 + c2 + 3] = (f16)v.w;
      }
    }
    __syncthreads();
    int mt = w & 1, ntp = w >> 1;              // 16 waves: 2 m-tiles x 8 nt-pairs
    f32x4 acc[2] = {};
    for (int ks = 0; ks < 12; ks++) {
      f16x8 a = *(const f16x8*)(&At[(mt * 16 + lr) * 392 + ks * 32 + lg * 8]);
      #pragma unroll
      for (int j = 0; j < 2; j++) {
        int nt = ntp * 2 + j;
        f16x8 bf = *(const f16x8*)(mlp2_p + ((size_t)((nt * 12 + ks) * 64 + lane) << 3));
        acc[j] = MFMA16(a, bf, acc[j]);
      }
    }
    #pragma unroll
    for (int j = 0; j < 2; j++) {
      int col = (ntp * 2 + j) * 16 + lr;
      float bias = mlp2b[col];
      #pragma unroll
      for (int rr = 0; rr < 4; rr++) {
        int item = i0 + mt * 16 + lg * 4 + rr;
        Sy[(size_t)item * 256 + col] = (f16)tanh_fast(acc[j][rr] + bias);
      }
    }
  }
}

// ============================================================================
// Per-(t,b) epilogue (16 rows/block, no atomics):
//  U = tanh(y@MNu.T+b); AW = softmax(U@r.T); AC = sum_f AW*MN;
//  Ut = tanh([y|AC]@MNu2.T+b); ypart = tanh(Ut@mlp1.T+b)
// ============================================================================
__global__ __launch_bounds__(512) void k_uacut(
    const f16* __restrict__ y_all, const f16* __restrict__ MNu_p,
    const float* __restrict__ MNub, const float* __restrict__ Rm,
    const f16* __restrict__ MN,
    const f16* __restrict__ MNu2_p, const float* __restrict__ MNu2b,
    const f16* __restrict__ mlp1_p, const float* __restrict__ mlp1b,
    float* __restrict__ ypart)
{
  __shared__ __align__(16) char smem[25088];
  int tid = threadIdx.x, w = tid >> 6, lane = tid & 63, lr = lane & 15, lg = lane >> 4;
  f16   (*Aty)[264] = (f16(*)[264])smem;
  float (*Uf)[136]  = (float(*)[136])(smem + 8448);
  f16   (*Utl)[264] = (f16(*)[264])(smem + 8448);
  float (*Lg)[10]   = (float(*)[10])(smem + 17152);
  float (*Aw)[10]   = (float(*)[10])(smem + 17792);
  f16   (*ACs)[136] = (f16(*)[136])(smem + 18432);
  int r0 = blockIdx.x * 16;
  {
    int r = tid >> 5, c = (tid & 31) * 8;
    f16x8 v = *(const f16x8*)(y_all + (size_t)(r0 + r) * 256 + c);
    *(f16x8*)(&Aty[r][c]) = v;
  }
  __syncthreads();
  {
    f32x4 acc = {};
    for (int ks = 0; ks < 8; ks++) {
      f16x8 a = *(const f16x8*)(&Aty[lr][ks * 32 + lg * 8]);
      f16x8 bf = *(const f16x8*)(MNu_p + ((size_t)((w * 8 + ks) * 64 + lane) << 3));
      acc = MFMA16(a, bf, acc);
    }
    int col = w * 16 + lr;
    float bias = MNub[col];
    #pragma unroll
    for (int rr = 0; rr < 4; rr++)
      Uf[lg * 4 + rr][col] = tanh_fast(acc[rr] + bias);
  }
  __syncthreads();
  if (tid < 160) {
    int row = tid / 10, f = tid - (tid / 10) * 10;
    float s = 0.f;
    for (int d = 0; d < 128; d++) s += Uf[row][d] * Rm[f * 128 + d];
    Lg[row][f] = s;
  }
  __syncthreads();
  if (tid < 16) {
    float m = -1e30f;
    #pragma unroll
    for (int f = 0; f < 10; f++) m = fmaxf(m, Lg[tid][f]);
    float e[10], s = 0.f;
    #pragma unroll
    for (int f = 0; f < 10; f++) { e[f] = __expf(Lg[tid][f] - m); s += e[f]; }
    float inv = 1.f / s;
    #pragma unroll
    for (int f = 0; f < 10; f++) Aw[tid][f] = e[f] * inv;
  }
  __syncthreads();
  if (tid < 256) {
    int row = tid >> 4, d0 = (tid & 15) * 8;
    float a[8] = {0,0,0,0,0,0,0,0};
    for (int f = 0; f < 10; f++) {
      float wgt = Aw[row][f];
      f16x8 mv = *(const f16x8*)(MN + (((size_t)(r0 + row)) * 10 + f) * 128 + d0);
      #pragma unroll
      for (int q = 0; q < 8; q++) a[q] += wgt * (float)mv[q];
    }
    f16x8 o;
    #pragma unroll
    for (int q = 0; q < 8; q++) o[q] = (f16)a[q];
    *(f16x8*)(&ACs[row][d0]) = o;
  }
  __syncthreads();
  {
    f32x4 acc[2] = {};
    for (int ks = 0; ks < 12; ks++) {
      f16x8 a = (ks < 8)
        ? *(const f16x8*)(&Aty[lr][ks * 32 + lg * 8])
        : *(const f16x8*)(&ACs[lr][(ks - 8) * 32 + lg * 8]);
      #pragma unroll
      for (int j = 0; j < 2; j++) {
        f16x8 bf = *(const f16x8*)(MNu2_p + ((size_t)(((w * 2 + j) * 12 + ks) * 64 + lane) << 3));
        acc[j] = MFMA16(a, bf, acc[j]);
      }
    }
    __syncthreads();   // Uf (overlaid) fully dead before Utl writes
    #pragma unroll
    for (int j = 0; j < 2; j++) {
      int col = (w * 2 + j) * 16 + lr;
      float bias = MNu2b[col];
      #pragma unroll
      for (int rr = 0; rr < 4; rr++)
        Utl[lg * 4 + rr][col] = (f16)tanh_fast(acc[j][rr] + bias);
    }
  }
  __syncthreads();
  {
    f32x4 acc2[2] = {};
    for (int ks = 0; ks < 8; ks++) {
      f16x8 a = *(const f16x8*)(&Utl[lr][ks * 32 + lg * 8]);
      #pragma unroll
      for (int j = 0; j < 2; j++) {
        f16x8 bf = *(const f16x8*)(mlp1_p + ((size_t)(((w * 2 + j) * 8 + ks) * 64 + lane) << 3));
        acc2[j] = MFMA16(a, bf, acc2[j]);
      }
    }
    #pragma unroll
    for (int j = 0; j < 2; j++) {
      int col = (w * 2 + j) * 16 + lr;
      float bias = mlp1b[col];
      #pragma unroll
      for (int rr = 0; rr < 4; rr++) {
        int row = r0 + lg * 4 + rr;
        ypart[(size_t)row * 256 + col] = tanh_fast(acc2[j][rr] + bias);
      }
    }
  }
}

// y[b][c] = (1/50) * sum_t ypart[t*256+b][c] -> d_out tail (f32) + f16 copy
__global__ __launch_bounds__(256) void k_yfin(
    const float* __restrict__ ypart, float* __restrict__ outy, f16* __restrict__ y16)
{
  int b = blockIdx.x, c = threadIdx.x;
  float s = 0.f;
  for (int t = 0; t < 50; t++) s += ypart[((size_t)t * 256 + b) * 256 + c];
  float v = s * (1.0f / 50.0f);
  outy[b * 256 + c] = v;
  y16[b * 256 + c] = (f16)v;
}

// ============================================================================
// SINGLE scores GEMM: stores raw f16 scores (into dead workspace span) and
// per-block per-row (max, sumexp) partials. 4KB LDS -> high occupancy.
// ============================================================================
__global__ __launch_bounds__(512) void k_scoreraw(
    const f16* __restrict__ y16, const f16* __restrict__ Sy,
    float* __restrict__ pmax, float* __restrict__ psum, f16* __restrict__ raw)
{
  __shared__ float pm[512], ps[512];
  int tid = threadIdx.x, w = tid >> 6, lane = tid & 63, lr = lane & 15, lg = lane >> 4;
  int i0 = blockIdx.x * 64;
  int mtb = (w >> 1) * 4, ntb = (w & 1) * 2;
  f32x4 acc[4][2] = {};
  for (int ks = 0; ks < 8; ks++) {
    f16x8 a[4];
    #pragma unroll
    for (int i = 0; i < 4; i++)
      a[i] = *(const f16x8*)(y16 + ((size_t)((mtb + i) * 16 + lr)) * 256 + ks * 32 + lg * 8);
    #pragma unroll
    for (int j = 0; j < 2; j++) {
      int item = i0 + (ntb + j) * 16 + lr;
      int ic = item < NITEMS ? item : (NITEMS - 1);
      f16x8 bv = *(const f16x8*)(Sy + (size_t)ic * 256 + ks * 32 + lg * 8);
      #pragma unroll
      for (int i = 0; i < 4; i++) acc[i][j] = MFMA16(a[i], bv, acc[i][j]);
    }
  }
  // raw f16 stores (2B x 16 consecutive lanes = 32B segments)
  #pragma unroll
  for (int i = 0; i < 4; i++)
    #pragma unroll
    for (int j = 0; j < 2; j++) {
      int c = i0 + (ntb + j) * 16 + lr;
      if (c < NITEMS) {
        #pragma unroll
        for (int rr = 0; rr < 4; rr++) {
          int row = (mtb + i) * 16 + lg * 4 + rr;
          raw[(size_t)row * NITEMS + c] = (f16)acc[i][j][rr];
        }
      }
    }
  // per-row partials (over this block's 64 items)
  {
    int item0 = i0 + ntb * 16 + lr, item1 = item0 + 16;
    bool v0 = item0 < NITEMS, v1 = item1 < NITEMS;
    #pragma unroll
    for (int i = 0; i < 4; i++)
      #pragma unroll
      for (int rr = 0; rr < 4; rr++) {
        float x0 = v0 ? acc[i][0][rr] : -1e30f;
        float x1 = v1 ? acc[i][1][rr] : -1e30f;
        float m = fmaxf(x0, x1);
        m = fmaxf(m, __shfl_xor(m, 1)); m = fmaxf(m, __shfl_xor(m, 2));
        m = fmaxf(m, __shfl_xor(m, 4)); m = fmaxf(m, __shfl_xor(m, 8));
        float s = (v0 ? __expf(x0 - m) : 0.f) + (v1 ? __expf(x1 - m) : 0.f);
        s += __shfl_xor(s, 1); s += __shfl_xor(s, 2);
        s += __shfl_xor(s, 4); s += __shfl_xor(s, 8);
        if (lr == 0) {
          int row = (mtb + i) * 16 + lg * 4 + rr;
          pm[(w & 1) * 256 + row] = m;
          ps[(w & 1) * 256 + row] = s;
        }
      }
  }
  __syncthreads();
  if (tid < 256) {
    float m0 = pm[tid], m1 = pm[256 + tid];
    float s0 = ps[tid], s1 = ps[256 + tid];
    float M = fmaxf(m0, m1);
    float S = s0 * __expf(m0 - M) + s1 * __expf(m1 - M);
    pmax[(size_t)tid * 1600 + blockIdx.x] = M;
    psum[(size_t)tid * 1600 + blockIdx.x] = S;
  }
}

// combine per-block partials -> lse[b]
__global__ __launch_bounds__(256) void k_lse(
    const float* __restrict__ pmax, const float* __restrict__ psum, float* __restrict__ lse)
{
  int b = blockIdx.x, tid = threadIdx.x;
  __shared__ float red[256];
  float m = -1e30f;
  for (int i = tid; i < NBLK4; i += 256) m = fmaxf(m, pmax[(size_t)b * 1600 + i]);
  red[tid] = m; __syncthreads();
  for (int s = 128; s > 0; s >>= 1) {
    if (tid < s) red[tid] = fmaxf(red[tid], red[tid + s]);
    __syncthreads();
  }
  float M = red[0]; __syncthreads();
  float s = 0.f;
  for (int i = tid; i < NBLK4; i += 256)
    s += psum[(size_t)b * 1600 + i] * __expf(pmax[(size_t)b * 1600 + i] - M);
  red[tid] = s; __syncthreads();
  for (int q = 128; q > 0; q >>= 1) {
    if (tid < q) red[tid] += red[tid + q];
    __syncthreads();
  }
  if (tid == 0) lse[b] = M + logf(red[0]);
}

// ============================================================================
// fix pass: out[row][c] = f32(raw[row][c]) - lse[row]; fully vectorized stream
// ============================================================================
__global__ __launch_bounds__(256) void k_fix(
    const f16* __restrict__ raw, const float* __restrict__ lse, float* __restrict__ out)
{
  int row = blockIdx.y;
  int idx = blockIdx.x * 256 + threadIdx.x;      // f16x8 units; 12500 per row
  if (idx < 12500) {
    float l = lse[row];
    f16x8 v = *(const f16x8*)(raw + (size_t)row * NITEMS + idx * 8);
    float4 o0, o1;
    o0.x = (float)v[0] - l; o0.y = (float)v[1] - l;
    o0.z = (float)v[2] - l; o0.w = (float)v[3] - l;
    o1.x = (float)v[4] - l; o1.y = (float)v[5] - l;
    o1.z = (float)v[6] - l; o1.w = (float)v[7] - l;
    float4* p = (float4*)(out + (size_t)row * NITEMS + idx * 8);
    p[0] = o0; p[1] = o1;
  }
}

// ============================================================================
extern "C" void kernel_launch(void* const* d_in, const int* in_sizes, int n_in,
                              void* d_out, int out_size, void* d_ws, size_t ws_size,
                              hipStream_t stream) {
  (void)in_sizes; (void)n_in; (void)out_size; (void)ws_size;
  const int*   X     = (const int*)d_in[0];
  const float* E     = (const float*)d_in[1];
  const float* KBE   = (const float*)d_in[2];
  const float* Rm    = (const float*)d_in[3];
  const float* Wih   = (const float*)d_in[4];
  const float* Whh   = (const float*)d_in[5];
  const float* bih   = (const float*)d_in[6];
  const float* bhh   = (const float*)d_in[7];
  const float* MNuW  = (const float*)d_in[8];
  const float* MNub  = (const float*)d_in[9];
  const float* MNu2W = (const float*)d_in[10];
  const float* MNu2b = (const float*)d_in[11];
  const float* MNeaW = (const float*)d_in[12];
  const float* MNeab = (const float*)d_in[13];
  const float* mlp1W = (const float*)d_in[14];
  const float* mlp1b = (const float*)d_in[15];
  const float* mlp2W = (const float*)d_in[16];
  const float* mlp2b = (const float*)d_in[17];

  char* ws = (char*)d_ws;
  f16*   Wih_p  = (f16*)(ws + OFF_WIH);
  f16*   Whh_p  = (f16*)(ws + OFF_WHH);
  f16*   MNu_p  = (f16*)(ws + OFF_MNU);
  f16*   MNu2_p = (f16*)(ws + OFF_MNU2);
  f16*   Wea_p  = (f16*)(ws + OFF_MNEA);
  f16*   mlp1_p = (f16*)(ws + OFF_MLP1);
  f16*   mlp2_p = (f16*)(ws + OFF_MLP2);
  f16*   gi2    = (f16*)(ws + OFF_GI);
  f16*   tv     = (f16*)(ws + OFF_TV);
  f16*   MN     = (f16*)(ws + OFF_MN);
  f16*   y_all  = (f16*)(ws + OFF_YALL);
  f16*   Sy     = (f16*)(ws + OFF_SY);
  float* ypart  = (float*)(ws + OFF_GI);   // reuse gi2 region (scan is done)
  f16*   raw    = (f16*)(ws + OFF_GI);     // raw f16 scores (after yfin; 51.2MB)
  f16*   y16    = (f16*)(ws + OFF_Y16);
  float* pmax   = (float*)(ws + OFF_PMAX);
  float* psum   = (float*)(ws + OFF_PSUM);
  float* lse    = (float*)(ws + OFF_LSE);
  float* outf   = (float*)d_out;

  k_pack<<<344, 256, 0, stream>>>(Wih, Whh, MNuW, MNu2W, MNeaW, mlp1W, mlp2W, (f16*)ws);
  k_giea<<<800, 512, 0, stream>>>(X, E, Wih_p, bih, bhh, gi2, KBE, Wea_p, MNeab, tv);
  k_fused<<<3317, 1024, 0, stream>>>(Whh_p, bhh, gi2, y_all, tv, Rm, MN,
                                     E, KBE, mlp2_p, mlp2b, Sy);
  k_uacut<<<800, 512, 0, stream>>>(y_all, MNu_p, MNub, Rm, MN,
                                   MNu2_p, MNu2b, mlp1_p, mlp1b, ypart);
  k_yfin<<<256, 256, 0, stream>>>(ypart, outf + 25600000, y16);
  k_scoreraw<<<NBLK4, 512, 0, stream>>>(y16, Sy, pmax, psum, raw);
  k_lse<<<256, 256, 0, stream>>>(pmax, psum, lse);
  dim3 gfix(49, 256);
  k_fix<<<gfix, 256, 0, stream>>>(raw, lse, outf);
}